// Round 8
// baseline (355.550 us; speedup 1.0000x reference)
//
#include <hip/hip_runtime.h>
#include <hip/hip_bf16.h>
#include <cstdint>
#include <cstddef>

#define B_    64
#define N_    2048
#define E_    32768            // edges per graph
#define DIM_  64
#define K1_   1639
#define K2_   1312
#define NTOT  (B_ * N_)        // 131072
#define ETOT  (B_ * E_)        // 2097152
#define N2TOT (B_ * K1_)       // 104896
#define NCLS  6
#define PB_   8                // pool blocks per graph (index-partitioned)
#define CHUNKS_ 16             // dst-chunks per graph
#define SLICES_ 16             // edge slices per graph in k_bucket
#define BCAP  3072             // bucket capacity (= SLICES_*REG_)
#define REG_  192              // per-slice region (mean 128, sd ~11 -> +5.8 sigma)

typedef float f4 __attribute__((ext_vector_type(4)));
typedef _Float16 h2 __attribute__((ext_vector_type(2)));
typedef _Float16 h8 __attribute__((ext_vector_type(8)));

static __device__ __forceinline__ float fdot2(h2 a, h2 b, float c) {
    return __builtin_amdgcn_fdot2(a, b, c, false);
}
static __device__ __forceinline__ h2 pkrtz(float a, float b) {
    return __builtin_bit_cast(h2, __builtin_amdgcn_cvt_pkrtz(a, b));
}
static __device__ __forceinline__ unsigned long long mk_key(float s, int i) {
    unsigned u = __float_as_uint(s);
    u = (u & 0x80000000u) ? ~u : (u | 0x80000000u);
    return ((unsigned long long)u << 11) | (unsigned long long)(2047 - i);
}

// ---------------- one-time W fragment prep: f16 hi/lo MFMA B-fragments --------------------
// layout: wf[stage][ks][nt][hl][lane] as h8 (16B); 1024 h8 per stage (16KB)
__launch_bounds__(128)
__global__ void k_wprep(const float* W1, const float* W2, h8* wf) {
    int t = threadIdx.x;
    int stage = t >> 6, lane = t & 63;
    const float* W = stage ? W2 : W1;
    int q = lane >> 4, c = lane & 15;
#pragma unroll
    for (int ks = 0; ks < 2; ks++)
#pragma unroll
        for (int nt = 0; nt < 4; nt++) {
            h8 h, l;
#pragma unroll
            for (int j = 0; j < 8; j++) {
                float wv = W[(ks * 32 + q * 8 + j) * 64 + nt * 16 + c];
                _Float16 hh = (_Float16)wv;
                h[j] = hh;
                l[j] = (_Float16)(wv - (float)hh);
            }
            wf[(size_t)stage * 1024 + (((ks * 4 + nt) * 2 + 0) * 64) + lane] = h;
            wf[(size_t)stage * 1024 + (((ks * 4 + nt) * 2 + 1) * 64) + lane] = l;
        }
}

// ---------------- bucket edges by (graph, dst-chunk) into slice-owned regions --------------
template<int STAGE>
__launch_bounds__(256)
__global__ void k_bucket(const int* src, const int* dst, const int* remap,
                         int* bcnt, unsigned int* blist) {
    const int LSTR = (STAGE == 1) ? 128 : 103;
    __shared__ unsigned int lb[CHUNKS_][REG_];
    __shared__ int lc[CHUNKS_];
    __shared__ int rm[N_];                     // stage2 only
    int b = blockIdx.x;
    int g = b & 63, slice = b >> 6;
    int tid = threadIdx.x;
    if (tid < CHUNKS_) lc[tid] = 0;
    if (STAGE == 2)
        for (int i = tid; i < N_; i += 256) rm[i] = remap[g * N_ + i];
    __syncthreads();
    const int ESL = E_ / SLICES_;              // 2048
    const int* sp = src + (size_t)g * E_ + slice * ESL;
    const int* dp = dst + (size_t)g * E_ + slice * ESL;
    int gbase = g * ((STAGE == 1) ? N_ : K1_);
    for (int e = tid * 4; e < ESL; e += 1024) {
        int4 ss = *(const int4*)&sp[e];
        int4 dd = *(const int4*)&dp[e];
#pragma unroll
        for (int t = 0; t < 4; t++) {
            int s = (&ss.x)[t], d = (&dd.x)[t];
            if (STAGE == 2) {
                s = rm[s & (N_ - 1)]; d = rm[d & (N_ - 1)];
                if ((s | d) < 0) continue;     // edge touches a dropped node
                s -= gbase; d -= gbase;
            } else {
                s &= (N_ - 1); d &= (N_ - 1);
            }
            int ch = d / LSTR;
            int dl = d - ch * LSTR;
            int p = atomicAdd(&lc[ch], 1);
            if (p < REG_) lb[ch][p] = ((unsigned)dl << 12) | (unsigned)s;
        }
    }
    __syncthreads();
    for (int ch = 0; ch < CHUNKS_; ch++) {
        int n = min(lc[ch], REG_);
        unsigned int* out = blist + (size_t)(g * CHUNKS_ + ch) * BCAP + slice * REG_;
        for (int i = tid; i < n; i += 256) out[i] = lb[ch][i];
    }
    if (tid < CHUNKS_) bcnt[(g * SLICES_ + slice) * CHUNKS_ + tid] = min(lc[tid], REG_);
}

// ---------------- counting-sort -> in-place compact CSR (byte offsets) + ninfo + prescale ---
template<int STAGE>
__launch_bounds__(256)
__global__ void k_sort(const int* bcnt, unsigned int* blist,
                       const float* xf, const unsigned int* xg,
                       unsigned int* xb, int* ninfo) {
    const int NL   = (STAGE == 1) ? N_ : K1_;
    const int LSTR = (STAGE == 1) ? 128 : 103;
    __shared__ int cnt[128], st[128], cur[128], cnt_s[SLICES_], stot[2];
    __shared__ float rsqv[128];
    __shared__ unsigned short sorted[BCAP];
    int b = blockIdx.x;
    int g = b & 63, ch = b >> 6;
    int tid = threadIdx.x;
    if (tid < 128) { cnt[tid] = 0; cur[tid] = 0; }
    if (tid < SLICES_) cnt_s[tid] = bcnt[(g * SLICES_ + tid) * CHUNKS_ + ch];
    __syncthreads();
    size_t bb = (size_t)(g * CHUNKS_ + ch) * BCAP;
    const unsigned int* bl = blist + bb;
    const int TOT = SLICES_ * REG_;            // 3072
    for (int i = tid; i < TOT; i += 256) {
        int s = i / REG_, j = i - s * REG_;
        if (j < cnt_s[s]) atomicAdd(&cnt[bl[i] >> 12], 1);
    }
    __syncthreads();
    if (tid < 128) {
        int v = cnt[tid];
        int l64 = tid & 63;
#pragma unroll
        for (int o = 1; o < 64; o <<= 1) {
            int t = __shfl_up(v, o);
            if (l64 >= o) v += t;
        }
        st[tid] = v;
        if (l64 == 63) stot[tid >> 6] = v;
    }
    __syncthreads();
    if (tid >= 64 && tid < 128) st[tid] += stot[0];
    __syncthreads();
    for (int i = tid; i < TOT; i += 256) {
        int s = i / REG_, j = i - s * REG_;
        if (j < cnt_s[s]) {
            unsigned pk = bl[i];
            int dl = (int)(pk >> 12);
            int p = st[dl] - cnt[dl] + atomicAdd(&cur[dl], 1);
            sorted[p] = (unsigned short)(pk & 0xFFFu);
        }
    }
    __syncthreads();
    int n = st[127];
    // store source-row BYTE offset within graph (local_idx * 128)
    for (int i = tid; i < n; i += 256) blist[bb + i] = ((unsigned int)sorted[i]) << 7;
    int lo = ch * LSTR;
    int nloc = min(LSTR, NL - lo);
    int gbase = g * NL;
    if (tid < nloc) {
        int node = gbase + lo + tid;
        int c = cnt[tid];
        int start = (int)bb + st[tid] - c;
        ninfo[node] = (start << 8) | min(c, 255);
        rsqv[tid] = rsqrtf((float)(c + 1));
    }
    __syncthreads();
    for (int idx = tid; idx < nloc * 32; idx += 256) {
        int nl = idx >> 5, f2 = idx & 31;
        int node = gbase + lo + nl;
        float sc = rsqv[nl];
        float2 v;
        if (STAGE == 1) {
            v = ((const float2*)xf)[(size_t)node * 32 + f2];
        } else {
            h2 hv = __builtin_bit_cast(h2, xg[(size_t)node * 32 + f2]);
            v.x = (float)hv.x; v.y = (float)hv.y;
        }
        h2 o = {(_Float16)(v.x * sc), (_Float16)(v.y * sc)};
        xb[(size_t)node * 32 + f2] = __builtin_bit_cast(unsigned int, o);
    }
}

// ---------------- FUSED gather-aggregate + MFMA conv --------------------------------------
// Agg (VECTORIZED GATHER): one node per wave at a time; per wave-instruction 8 edges are
// fetched as dwordx4 (lane L reads bytes [16*(L&7),+16) of edge j+L/8 -> 1KB/instr, each
// byte once). Edge offsets: up to 64 CSR entries loaded ONCE per node into a register
// (lane L holds entry L), distributed per-iteration via one __shfl. Per-node epilogue:
// 3-round shfl_xor (8/16/32) reduction + self row + rd scale; lanes 0..7 write the
// swizzled LDS row. Round 4-7 evidence: per-edge bpermute+addressing was the cost, not
// load scheduling; this divides VMEM instrs by 4 and DS ops by ~4.
// Conv: MFMA f16 hi/lo with W fragments pre-built by k_wprep, staged in LDS (16KB).
template<bool GATE>
__launch_bounds__(256, 4)
__global__ void k_aggconv(const unsigned int* xb, const int* ninfo, const unsigned int* csr,
                          const h8* wfrag, const float* bias, const float* pvec,
                          float* y, float* score) {
    __shared__ float4 ls4[1024];               // 64 rows x 16 float4 (swizzled), 16KB
    __shared__ h8 wlds[2][4][2][64];           // [ks][nt][hl][lane], 16KB
    int b = blockIdx.x;
    int wg;
    if (GATE) {                                 // 1639 blocks: bijective m204 (q=204,r=7)
        int xcd = b & 7, k = b >> 3;
        wg = (xcd < 7 ? xcd * 205 : 1435 + (xcd - 7) * 204) + k;
    } else {                                    // 2048 blocks: 8 graphs per XCD
        wg = (b & 7) * 256 + (b >> 3);
    }
    int tid = threadIdx.x;
    int wid = tid >> 6, lane = tid & 63;
    int grp = lane >> 3;                       // edge sub-index within an 8-edge batch
    int l16 = (lane & 7) * 16;                 // byte slice within a row

    // stage W fragments into LDS (covered by the phase barrier below)
    {
        const h8* wsrc = wfrag + (GATE ? 1024 : 0);
        h8* wd = (h8*)wlds;
        for (int i = tid; i < 1024; i += 256) wd[i] = wsrc[i];
    }

    const char* xbb = (const char*)xb;
    const h2 one0  = {(_Float16)1.0f, (_Float16)0.0f};
    const h2 zero1 = {(_Float16)0.0f, (_Float16)1.0f};
    int rb = wg * 64 + wid * 16;
    int g0 = 0, bnd = 0;
    if (GATE) { g0 = (wg * 64) / K1_; bnd = (g0 + 1) * K1_; }

    int niv = 0;
    if (lane < 16) niv = ninfo[rb + lane];
    // prologue: node 0's info + its CSR entries (lane L holds entry L, L < min(cnt,64))
    int ni = __builtin_amdgcn_readfirstlane(__shfl(niv, 0));
    unsigned eo = 0;
    { int ec = min(ni & 255, 64); if (lane < ec) eo = csr[(ni >> 8) + lane]; }

    // ---- phase 1: aggregate the wave's 16 rows into LDS ----
#pragma unroll 1
    for (int p = 0; p < 16; p++) {
        int cnt = ni & 255, base = ni >> 8;
        int node = rb + p;
        int gbb;
        if (GATE) { int gr = (node >= bnd) ? (g0 + 1) : g0; gbb = gr * (K1_ * 128); }
        else       gbb = (node & ~(N_ - 1)) << 7;
        const char* gx = xbb + gbb;            // uniform graph base in xb (saddr)
        // prefetch next node's info + CSR entries
        int ni_n = 0; unsigned eo_n = 0;
        if (p < 15) {
            ni_n = __builtin_amdgcn_readfirstlane(__shfl(niv, p + 1));
            int ec = min(ni_n & 255, 64);
            if (lane < ec) eo_n = csr[(ni_n >> 8) + lane];
        }
        // self row (issued early; consumed after the reduction)
        uint4 su = *(const uint4*)(xbb + (size_t)(unsigned)(node * 128 + l16));
        float aA[4] = {0.f, 0.f, 0.f, 0.f};
        float aB[4] = {0.f, 0.f, 0.f, 0.f};
        int nv = min(cnt, 64);
        for (int t = 0; t * 8 < nv; t++) {
            int idx = t * 8 + grp;
            unsigned ro = __shfl(eo, idx);     // one offset broadcast per 8 edges
            if (idx < cnt) {
                uint4 v = *(const uint4*)(gx + (ro + (unsigned)l16));
#pragma unroll
                for (int w = 0; w < 4; w++) {
                    h2 h = __builtin_bit_cast(h2, (&v.x)[w]);
                    aA[w] = fdot2(h, one0,  aA[w]);
                    aB[w] = fdot2(h, zero1, aB[w]);
                }
            }
        }
        for (int j = 64; j < cnt; j += 8) {    // rare: degree > 64
            int idx = j + grp;
            if (idx < cnt) {
                unsigned ro = csr[base + idx];
                uint4 v = *(const uint4*)(gx + (ro + (unsigned)l16));
#pragma unroll
                for (int w = 0; w < 4; w++) {
                    h2 h = __builtin_bit_cast(h2, (&v.x)[w]);
                    aA[w] = fdot2(h, one0,  aA[w]);
                    aB[w] = fdot2(h, zero1, aB[w]);
                }
            }
        }
        // reduce the 8 edge-groups (stride 8/16/32)
#pragma unroll
        for (int m = 8; m < 64; m <<= 1) {
#pragma unroll
            for (int w = 0; w < 4; w++) {
                aA[w] += __shfl_xor(aA[w], m);
                aB[w] += __shfl_xor(aB[w], m);
            }
        }
        if (lane < 8) {                        // lane s owns features [8s, 8s+8)
#pragma unroll
            for (int w = 0; w < 4; w++) {      // add self-loop term
                h2 h = __builtin_bit_cast(h2, (&su.x)[w]);
                aA[w] = fdot2(h, one0,  aA[w]);
                aB[w] = fdot2(h, zero1, aB[w]);
            }
            float rd = rsqrtf((float)(cnt + 1));
            int rloc = wid * 16 + p;
            int c0 = (2 * lane)     ^ (rloc & 7);
            int c1 = (2 * lane + 1) ^ (rloc & 7);
            ls4[rloc * 16 + c0] = make_float4(aA[0] * rd, aB[0] * rd, aA[1] * rd, aB[1] * rd);
            ls4[rloc * 16 + c1] = make_float4(aA[2] * rd, aB[2] * rd, aA[3] * rd, aB[3] * rd);
        }
        ni = ni_n; eo = eo_n;
    }
    __syncthreads();

    // ---- phase 2: conv = relu(agg @ W + b), score = tanh(conv.p/||p||) ----
    int q = lane >> 4, c = lane & 15;
    int rl16 = (wid * 16 + c) * 16;            // float4 row base in LDS
    int cx = c & 7;
    h8 ah[2], al[2];
#pragma unroll
    for (int ks = 0; ks < 2; ks++) {
        float4 v0 = ls4[rl16 + ((ks * 8 + q * 2 + 0) ^ cx)];
        float4 v1 = ls4[rl16 + ((ks * 8 + q * 2 + 1) ^ cx)];
        float vv[8] = {v0.x, v0.y, v0.z, v0.w, v1.x, v1.y, v1.z, v1.w};
        h8 h, l;
#pragma unroll
        for (int j = 0; j < 8; j += 2) {
            h2 hp = pkrtz(vv[j], vv[j + 1]);
            float r0 = vv[j]     - (float)hp.x;
            float r1 = vv[j + 1] - (float)hp.y;
            h2 lp = pkrtz(r0, r1);
            h[j] = hp.x; h[j + 1] = hp.y;
            l[j] = lp.x; l[j + 1] = lp.y;
        }
        ah[ks] = h; al[ks] = l;
    }
    float pp = 0.f;
#pragma unroll
    for (int i = 0; i < DIM_; i++) pp += pvec[i] * pvec[i];
    float rpn = rsqrtf(pp);
    float dot[4] = {0.f, 0.f, 0.f, 0.f};
#pragma unroll
    for (int nt = 0; nt < 4; nt++) {
        f4 acc = {0.f, 0.f, 0.f, 0.f};
#pragma unroll
        for (int ks = 0; ks < 2; ks++) {
            h8 wh = wlds[ks][nt][0][lane];
            h8 wl = wlds[ks][nt][1][lane];
            acc = __builtin_amdgcn_mfma_f32_16x16x32_f16(ah[ks], wh, acc, 0, 0, 0);
            acc = __builtin_amdgcn_mfma_f32_16x16x32_f16(ah[ks], wl, acc, 0, 0, 0);
            acc = __builtin_amdgcn_mfma_f32_16x16x32_f16(al[ks], wh, acc, 0, 0, 0);
        }
        float bcol = bias[nt * 16 + c];
        float pcol = pvec[nt * 16 + c];
        float st[4];
#pragma unroll
        for (int reg = 0; reg < 4; reg++) {
            float v = fmaxf(acc[reg] + bcol, 0.f);
            st[reg] = v;
            dot[reg] += v * pcol;
        }
#pragma unroll
        for (int reg = 0; reg < 4; reg++)
            y[(size_t)(wg * 64 + wid * 16 + q * 4 + reg) * DIM_ + nt * 16 + c] = st[reg];
    }
#pragma unroll
    for (int m = 1; m < 16; m <<= 1) {
#pragma unroll
        for (int reg = 0; reg < 4; reg++) dot[reg] += __shfl_xor(dot[reg], m);
    }
    if (c == 0) {
#pragma unroll
        for (int reg = 0; reg < 4; reg++)
            score[wg * 64 + wid * 16 + q * 4 + reg] = tanhf(dot[reg] * rpn);
    }
}

// ---------------- exact K-th-largest key per graph (6-pass radix) --------------
template<int STAGE>
__launch_bounds__(256)
__global__ void k_thresh(const float* score, unsigned long long* thresh) {
    const int Nin = (STAGE == 1) ? N_ : K1_;
    const int K   = (STAGE == 1) ? K1_ : K2_;
    __shared__ unsigned long long keys[N_];
    __shared__ int bins[256], wsum[4];
    __shared__ unsigned long long s_prefix;
    __shared__ int s_need;
    int g = blockIdx.x, tid = threadIdx.x;
    int l64 = tid & 63, wid = tid >> 6;
    const float* sg = score + (size_t)g * Nin;
    for (int i = tid; i < Nin; i += 256) keys[i] = mk_key(sg[i], i);
    if (tid == 0) { s_need = K; s_prefix = 0ull; }
    __syncthreads();
    for (int shift = 40; shift >= 0; shift -= 8) {
        bins[tid] = 0;
        __syncthreads();
        unsigned long long pref = s_prefix;
        int need = s_need;
        int hi = shift + 8;
        for (int i = tid; i < Nin; i += 256) {
            unsigned long long k = keys[i];
            if ((k >> hi) == pref) atomicAdd(&bins[(int)((k >> shift) & 255)], 1);
        }
        __syncthreads();
        int mine = bins[tid];
        int v = mine;
#pragma unroll
        for (int o = 1; o < 64; o <<= 1) {     // wave suffix scan
            int t = __shfl_down(v, o);
            if (l64 + o < 64) v += t;
        }
        if (l64 == 0) wsum[wid] = v;
        __syncthreads();
        for (int w = wid + 1; w < 4; w++) v += wsum[w];
        int nxt = v - mine;
        if (v >= need && nxt < need) {         // exactly one tid matches
            s_prefix = (pref << 8) | (unsigned long long)tid;
            s_need = need - nxt;
        }
        __syncthreads();
    }
    if (tid == 0) thresh[g] = s_prefix;
}

// ---------------- pool (+rank/newid/xg in stage1), PB_ blocks/graph, threshold handoff ------
template<int STAGE>
__launch_bounds__(256)
__global__ void k_pool(const float* score, const float* conv, const unsigned long long* thresh,
                       int* new_id, unsigned int* xg, float* part) {
    const int Nin = (STAGE == 1) ? N_ : K1_;
    const int RNG = (STAGE == 1) ? (N_ / PB_) : ((K1_ + PB_ - 1) / PB_);  // 256 / 205
    __shared__ int rnk[256];
    __shared__ unsigned char keepf[256];
    __shared__ int wsum[4], s_base[4];
    __shared__ float rmx[4][64], rsm[4][64];
    int b = blockIdx.x;
    int g = b & 63, pb = b >> 6;
    int tid = threadIdx.x;
    int l64 = tid & 63, wid = tid >> 6;
    const float* sg = score + (size_t)g * Nin;
    unsigned long long T = thresh[g];
    int R0 = pb * RNG;
    int R1 = min(R0 + RNG, Nin);
    if (STAGE == 1) {
        int cb = 0;
        for (int i = tid; i < R0; i += 256) cb += (mk_key(sg[i], i) >= T) ? 1 : 0;
#pragma unroll
        for (int o = 32; o; o >>= 1) cb += __shfl_down(cb, o);
        if (l64 == 0) s_base[wid] = cb;
        int i = R0 + tid;
        int keep = (i < R1 && mk_key(sg[i], i) >= T) ? 1 : 0;
        keepf[tid] = (unsigned char)keep;
        int v = keep;
#pragma unroll
        for (int o = 1; o < 64; o <<= 1) {
            int t = __shfl_up(v, o);
            if (l64 >= o) v += t;
        }
        if (l64 == 63) wsum[wid] = v;
        __syncthreads();
        int base = s_base[0] + s_base[1] + s_base[2] + s_base[3];
        int wbase = 0;
        for (int w = 0; w < wid; w++) wbase += wsum[w];
        int r = base + wbase + v - keep;
        rnk[tid] = r;
        if (i < Nin) new_id[g * N_ + i] = keep ? (g * K1_ + r) : -1;
    } else {
        int i = R0 + tid;
        keepf[tid] = (unsigned char)((i < R1 && mk_key(sg[i], i) >= T) ? 1 : 0);
    }
    __syncthreads();
    float mx = -3.402823466e38f, sm = 0.f;
    for (int i = R0 + wid; i < R1; i += 4) {
        if (!keepf[i - R0]) continue;
        float val = sg[i];
        float v = conv[(size_t)(g * Nin + i) * DIM_ + l64] * val;
        mx = fmaxf(mx, v);
        sm += v;
        if (STAGE == 1) {
            float vo = __shfl_xor(v, 1);
            if (!(l64 & 1)) {
                h2 pk2 = {(_Float16)v, (_Float16)vo};
                xg[(size_t)(g * K1_ + rnk[i - R0]) * 32 + (l64 >> 1)] =
                    __builtin_bit_cast(unsigned int, pk2);
            }
        }
    }
    rmx[wid][l64] = mx; rsm[wid][l64] = sm;
    __syncthreads();
    if (wid == 0) {
        mx = fmaxf(fmaxf(rmx[0][l64], rmx[1][l64]), fmaxf(rmx[2][l64], rmx[3][l64]));
        sm = rsm[0][l64] + rsm[1][l64] + rsm[2][l64] + rsm[3][l64];
        part[((size_t)(g * PB_ + pb) * 2 + 0) * 64 + l64] = mx;
        part[((size_t)(g * PB_ + pb) * 2 + 1) * 64 + l64] = sm;
    }
}

// ---------------- MLP head (combines both stages' partials) ----------------
__launch_bounds__(64)
__global__ void k_head(const float* part1, const float* part2,
                       const float* l1w, const float* l1b,
                       const float* l2w, const float* l2b, float* out) {
    __shared__ float h[128];
    __shared__ float h1[64];
    int g = blockIdx.x, t = threadIdx.x;
    float mx1 = -3.402823466e38f, sm1 = 0.f, mx2 = -3.402823466e38f, sm2 = 0.f;
#pragma unroll
    for (int c = 0; c < PB_; c++) {
        mx1 = fmaxf(mx1, part1[((size_t)(g * PB_ + c) * 2 + 0) * 64 + t]);
        sm1 += part1[((size_t)(g * PB_ + c) * 2 + 1) * 64 + t];
        mx2 = fmaxf(mx2, part2[((size_t)(g * PB_ + c) * 2 + 0) * 64 + t]);
        sm2 += part2[((size_t)(g * PB_ + c) * 2 + 1) * 64 + t];
    }
    h[t]      = mx1 + mx2;
    h[t + 64] = sm1 / (float)K1_ + sm2 / (float)K2_;
    __syncthreads();
    float acc = l1b[t];
#pragma unroll 8
    for (int i = 0; i < 128; i++) acc += h[i] * l1w[i * 64 + t];
    h1[t] = fmaxf(acc, 0.0f);
    __syncthreads();
    if (t < NCLS) {
        float o = l2b[t];
#pragma unroll
        for (int i = 0; i < 64; i++) o += h1[i] * l2w[i * NCLS + t];
        out[g * NCLS + t] = o;
    }
}

extern "C" void kernel_launch(void* const* d_in, const int* in_sizes, int n_in,
                              void* d_out, int out_size, void* d_ws, size_t ws_size,
                              hipStream_t stream) {
    const float* x   = (const float*)d_in[0];
    const int*   ei  = (const int*)d_in[1];
    const int*   src = ei;
    const int*   dst = ei + ETOT;
    const float* W1  = (const float*)d_in[3];
    const float* b1  = (const float*)d_in[4];
    const float* p1  = (const float*)d_in[5];
    const float* W2  = (const float*)d_in[6];
    const float* b2  = (const float*)d_in[7];
    const float* p2  = (const float*)d_in[8];
    const float* l1w = (const float*)d_in[9];
    const float* l1b = (const float*)d_in[10];
    const float* l2w = (const float*)d_in[11];
    const float* l2b = (const float*)d_in[12];
    (void)in_sizes; (void)n_in; (void)out_size; (void)ws_size;

    // workspace layout (~92 MB); xg aliases bufB (dead until aggconv2 writes it)
    char* ws = (char*)d_ws;
    size_t off = 0;
    auto alloc = [&](size_t bytes) -> void* {
        void* p = ws + off;
        off = (off + bytes + 255) & ~(size_t)255;
        return p;
    };
    float*              bufA   = (float*)             alloc((size_t)NTOT  * DIM_ * 4);
    float*              bufB   = (float*)             alloc((size_t)N2TOT * DIM_ * 4);
    unsigned int*       blist  = (unsigned int*)      alloc((size_t)B_ * CHUNKS_ * BCAP * 4);
    unsigned int*       xb     = (unsigned int*)      alloc((size_t)NTOT * 32 * 4);
    int*                bcnt   = (int*)               alloc((size_t)B_ * SLICES_ * CHUNKS_ * 4);
    int*                ninfo  = (int*)               alloc((size_t)NTOT * 4);
    float*              score  = (float*)             alloc((size_t)NTOT * 4);
    int*                newid  = (int*)               alloc((size_t)NTOT * 4);
    unsigned long long* thr    = (unsigned long long*)alloc((size_t)B_ * 8);
    float*              part1  = (float*)             alloc((size_t)B_ * PB_ * 128 * 4);
    float*              part2  = (float*)             alloc((size_t)B_ * PB_ * 128 * 4);
    h8*                 wfrag  = (h8*)                alloc((size_t)2048 * 16);
    unsigned int*       xg     = (unsigned int*)bufB;   // alias

    // ---- one-time W fragment prep ----
    k_wprep<<<1, 128, 0, stream>>>(W1, W2, wfrag);

    // ---- stage 1 ----
    k_bucket<1><<<B_ * SLICES_, 256, 0, stream>>>(src, dst, nullptr, bcnt, blist);
    k_sort<1><<<B_ * CHUNKS_, 256, 0, stream>>>(bcnt, blist, x, nullptr, xb, ninfo);
    k_aggconv<false><<<NTOT / 64, 256, 0, stream>>>(xb, ninfo, blist, wfrag, b1, p1, bufA, score);
    k_thresh<1><<<B_, 256, 0, stream>>>(score, thr);
    k_pool<1><<<B_ * PB_, 256, 0, stream>>>(score, bufA, thr, newid, xg, part1);

    // ---- stage 2 ----
    k_bucket<2><<<B_ * SLICES_, 256, 0, stream>>>(src, dst, newid, bcnt, blist);
    k_sort<2><<<B_ * CHUNKS_, 256, 0, stream>>>(bcnt, blist, nullptr, xg, xb, ninfo);
    k_aggconv<true><<<N2TOT / 64, 256, 0, stream>>>(xb, ninfo, blist, wfrag, b2, p2, bufB, score);
    k_thresh<2><<<B_, 256, 0, stream>>>(score, thr);
    k_pool<2><<<B_ * PB_, 256, 0, stream>>>(score, bufB, thr, nullptr, nullptr, part2);

    // ---- head (combines both stages' partials) ----
    k_head<<<B_, 64, 0, stream>>>(part1, part2, l1w, l1b, l2w, l2b, (float*)d_out);
}

// Round 9
// 294.706 us; speedup vs baseline: 1.2065x; 1.2065x over previous
//
#include <hip/hip_runtime.h>
#include <hip/hip_bf16.h>
#include <cstdint>
#include <cstddef>

#define B_    64
#define N_    2048
#define E_    32768            // edges per graph
#define DIM_  64
#define K1_   1639
#define K2_   1312
#define NTOT  (B_ * N_)        // 131072
#define ETOT  (B_ * E_)        // 2097152
#define N2TOT (B_ * K1_)       // 104896
#define NCLS  6
#define PB_   8                // pool blocks per graph (index-partitioned)
#define CHUNKS_ 16             // dst-chunks per graph
#define SLICES_ 16             // edge slices per graph in k_bucket
#define BCAP  3072             // bucket capacity (= SLICES_*REG_)
#define REG_  192              // per-slice region (mean 128, sd ~11 -> +5.8 sigma)

typedef float f4 __attribute__((ext_vector_type(4)));
typedef _Float16 h2 __attribute__((ext_vector_type(2)));
typedef _Float16 h8 __attribute__((ext_vector_type(8)));

static __device__ __forceinline__ float fdot2(h2 a, h2 b, float c) {
    return __builtin_amdgcn_fdot2(a, b, c, false);
}
static __device__ __forceinline__ h2 pkrtz(float a, float b) {
    return __builtin_bit_cast(h2, __builtin_amdgcn_cvt_pkrtz(a, b));
}
static __device__ __forceinline__ unsigned long long mk_key(float s, int i) {
    unsigned u = __float_as_uint(s);
    u = (u & 0x80000000u) ? ~u : (u | 0x80000000u);
    return ((unsigned long long)u << 11) | (unsigned long long)(2047 - i);
}

// ---------------- one-time W fragment prep: f16 hi/lo MFMA B-fragments --------------------
// layout: wf[stage][ks][nt][hl][lane] as h8 (16B); 1024 h8 per stage (16KB)
__launch_bounds__(128)
__global__ void k_wprep(const float* W1, const float* W2, h8* wf) {
    int t = threadIdx.x;
    int stage = t >> 6, lane = t & 63;
    const float* W = stage ? W2 : W1;
    int q = lane >> 4, c = lane & 15;
#pragma unroll
    for (int ks = 0; ks < 2; ks++)
#pragma unroll
        for (int nt = 0; nt < 4; nt++) {
            h8 h, l;
#pragma unroll
            for (int j = 0; j < 8; j++) {
                float wv = W[(ks * 32 + q * 8 + j) * 64 + nt * 16 + c];
                _Float16 hh = (_Float16)wv;
                h[j] = hh;
                l[j] = (_Float16)(wv - (float)hh);
            }
            wf[(size_t)stage * 1024 + (((ks * 4 + nt) * 2 + 0) * 64) + lane] = h;
            wf[(size_t)stage * 1024 + (((ks * 4 + nt) * 2 + 1) * 64) + lane] = l;
        }
}

// ---------------- bucket edges by (graph, dst-chunk) into slice-owned regions --------------
template<int STAGE>
__launch_bounds__(256)
__global__ void k_bucket(const int* src, const int* dst, const int* remap,
                         int* bcnt, unsigned int* blist) {
    const int LSTR = (STAGE == 1) ? 128 : 103;
    __shared__ unsigned int lb[CHUNKS_][REG_];
    __shared__ int lc[CHUNKS_];
    __shared__ int rm[N_];                     // stage2 only
    int b = blockIdx.x;
    int g = b & 63, slice = b >> 6;
    int tid = threadIdx.x;
    if (tid < CHUNKS_) lc[tid] = 0;
    if (STAGE == 2)
        for (int i = tid; i < N_; i += 256) rm[i] = remap[g * N_ + i];
    __syncthreads();
    const int ESL = E_ / SLICES_;              // 2048
    const int* sp = src + (size_t)g * E_ + slice * ESL;
    const int* dp = dst + (size_t)g * E_ + slice * ESL;
    int gbase = g * ((STAGE == 1) ? N_ : K1_);
    for (int e = tid * 4; e < ESL; e += 1024) {
        int4 ss = *(const int4*)&sp[e];
        int4 dd = *(const int4*)&dp[e];
#pragma unroll
        for (int t = 0; t < 4; t++) {
            int s = (&ss.x)[t], d = (&dd.x)[t];
            if (STAGE == 2) {
                s = rm[s & (N_ - 1)]; d = rm[d & (N_ - 1)];
                if ((s | d) < 0) continue;     // edge touches a dropped node
                s -= gbase; d -= gbase;
            } else {
                s &= (N_ - 1); d &= (N_ - 1);
            }
            int ch = d / LSTR;
            int dl = d - ch * LSTR;
            int p = atomicAdd(&lc[ch], 1);
            if (p < REG_) lb[ch][p] = ((unsigned)dl << 12) | (unsigned)s;
        }
    }
    __syncthreads();
    for (int ch = 0; ch < CHUNKS_; ch++) {
        int n = min(lc[ch], REG_);
        unsigned int* out = blist + (size_t)(g * CHUNKS_ + ch) * BCAP + slice * REG_;
        for (int i = tid; i < n; i += 256) out[i] = lb[ch][i];
    }
    if (tid < CHUNKS_) bcnt[(g * SLICES_ + slice) * CHUNKS_ + tid] = min(lc[tid], REG_);
}

// ---------------- counting-sort -> in-place compact CSR (byte offsets) + ninfo + prescale ---
template<int STAGE>
__launch_bounds__(256)
__global__ void k_sort(const int* bcnt, unsigned int* blist,
                       const float* xf, const unsigned int* xg,
                       unsigned int* xb, int* ninfo) {
    const int NL   = (STAGE == 1) ? N_ : K1_;
    const int LSTR = (STAGE == 1) ? 128 : 103;
    __shared__ int cnt[128], st[128], cur[128], cnt_s[SLICES_], stot[2];
    __shared__ float rsqv[128];
    __shared__ unsigned short sorted[BCAP];
    int b = blockIdx.x;
    int g = b & 63, ch = b >> 6;
    int tid = threadIdx.x;
    if (tid < 128) { cnt[tid] = 0; cur[tid] = 0; }
    if (tid < SLICES_) cnt_s[tid] = bcnt[(g * SLICES_ + tid) * CHUNKS_ + ch];
    __syncthreads();
    size_t bb = (size_t)(g * CHUNKS_ + ch) * BCAP;
    const unsigned int* bl = blist + bb;
    const int TOT = SLICES_ * REG_;            // 3072
    for (int i = tid; i < TOT; i += 256) {
        int s = i / REG_, j = i - s * REG_;
        if (j < cnt_s[s]) atomicAdd(&cnt[bl[i] >> 12], 1);
    }
    __syncthreads();
    if (tid < 128) {
        int v = cnt[tid];
        int l64 = tid & 63;
#pragma unroll
        for (int o = 1; o < 64; o <<= 1) {
            int t = __shfl_up(v, o);
            if (l64 >= o) v += t;
        }
        st[tid] = v;
        if (l64 == 63) stot[tid >> 6] = v;
    }
    __syncthreads();
    if (tid >= 64 && tid < 128) st[tid] += stot[0];
    __syncthreads();
    for (int i = tid; i < TOT; i += 256) {
        int s = i / REG_, j = i - s * REG_;
        if (j < cnt_s[s]) {
            unsigned pk = bl[i];
            int dl = (int)(pk >> 12);
            int p = st[dl] - cnt[dl] + atomicAdd(&cur[dl], 1);
            sorted[p] = (unsigned short)(pk & 0xFFFu);
        }
    }
    __syncthreads();
    int n = st[127];
    // store source-row BYTE offset within graph (local_idx * 128)
    for (int i = tid; i < n; i += 256) blist[bb + i] = ((unsigned int)sorted[i]) << 7;
    int lo = ch * LSTR;
    int nloc = min(LSTR, NL - lo);
    int gbase = g * NL;
    if (tid < nloc) {
        int node = gbase + lo + tid;
        int c = cnt[tid];
        int start = (int)bb + st[tid] - c;
        ninfo[node] = (start << 8) | min(c, 255);
        rsqv[tid] = rsqrtf((float)(c + 1));
    }
    __syncthreads();
    for (int idx = tid; idx < nloc * 32; idx += 256) {
        int nl = idx >> 5, f2 = idx & 31;
        int node = gbase + lo + nl;
        float sc = rsqv[nl];
        float2 v;
        if (STAGE == 1) {
            v = ((const float2*)xf)[(size_t)node * 32 + f2];
        } else {
            h2 hv = __builtin_bit_cast(h2, xg[(size_t)node * 32 + f2]);
            v.x = (float)hv.x; v.y = (float)hv.y;
        }
        h2 o = {(_Float16)(v.x * sc), (_Float16)(v.y * sc)};
        xb[(size_t)node * 32 + f2] = __builtin_bit_cast(unsigned int, o);
    }
}

// ---------------- FUSED gather-aggregate + MFMA conv --------------------------------------
// Agg: wave wid aggregates rows [wid*16,+16) two at a time (half-wave chains), f16 rows
// accumulated via v_dot2_f32_f16, byte-offset CSR addressing (round-5 structure = best).
// OCCUPANCY FIX (r8 evidence): the W-fragment LDS cache (16KB) halved block residency
// (LDS 32KB -> 5 blocks/CU); the aggregate phase is a latency chain that scales with
// resident waves. Dropped wlds -> LDS 16KB; phase 2 reads wfrag straight from global
// (32KB table, L1/L2-hit, 16x16B per thread once per block). launch_bounds(256,8)
// requests full 8-blocks/CU occupancy (VGPR 44 fits the 64-reg budget).
template<bool GATE>
__launch_bounds__(256, 8)
__global__ void k_aggconv(const unsigned int* xb, const int* ninfo, const unsigned int* csr,
                          const h8* wfrag, const float* bias, const float* pvec,
                          float* y, float* score) {
    __shared__ float4 ls4[1024];               // 64 rows x 64 floats (swizzled), 16KB
    float* ls = (float*)ls4;
    int b = blockIdx.x;
    int wg;
    if (GATE) {                                 // 1639 blocks: bijective m204 (q=204,r=7)
        int xcd = b & 7, k = b >> 3;
        wg = (xcd < 7 ? xcd * 205 : 1435 + (xcd - 7) * 204) + k;
    } else {                                    // 2048 blocks: 8 graphs per XCD
        wg = (b & 7) * 256 + (b >> 3);
    }
    int tid = threadIdx.x;
    int wid = tid >> 6, lane = tid & 63;
    int half = lane >> 5, l32 = lane & 31, hbase = half << 5;
    int l32_4 = l32 << 2;
    int rowbase = wg * 64 + wid * 16;

    const char* xbb = (const char*)xb;
    const h2 one0  = {(_Float16)1.0f, (_Float16)0.0f};
    const h2 zero1 = {(_Float16)0.0f, (_Float16)1.0f};
    int g0 = 0, bnd = 0;
    if (GATE) { g0 = (wg * 64) / K1_; bnd = (g0 + 1) * K1_; }
    auto gbyte = [&](int node) -> int {        // byte base of the node's graph in xb
        if (GATE) { int gr = (node >= bnd) ? (g0 + 1) : g0; return gr * (K1_ * 128); }
        return (node & ~(N_ - 1)) << 7;
    };

    // ---- phase 1: aggregate the wave's 16 rows into LDS ----
    int niv = 0;
    if (lane < 16) niv = ninfo[rowbase + lane];
    int ni = __shfl(niv, half);                // pair 0 info
    int gbb = gbyte(rowbase + half);
    int sv = 0;
    { int c0 = ni & 255; if (l32 < c0) sv = (int)csr[(ni >> 8) + l32] + gbb; }
#pragma unroll 1
    for (int p = 0; p < 8; p++) {
        int cnt = ni & 255, base = ni >> 8;
        int ni_n = 0, sv_n = 0, gbb_n = 0;     // prefetch next pair's first csr chunk
        if (p < 7) {
            ni_n = __shfl(niv, 2 * (p + 1) + half);
            gbb_n = gbyte(rowbase + 2 * (p + 1) + half);
            int cn = ni_n & 255;
            if (l32 < cn) sv_n = (int)csr[(ni_n >> 8) + l32] + gbb_n;
        }
        int rloc = wid * 16 + 2 * p + half;    // LDS row 0..63
        int node = wg * 64 + rloc;
        unsigned selfu = *(const unsigned*)(xbb + (unsigned)(node * 128 + l32_4));
        float acx[4] = {0.f, 0.f, 0.f, 0.f};
        float acy[4] = {0.f, 0.f, 0.f, 0.f};
        int svc = sv;
        for (int chunk = 0; chunk < cnt; chunk += 32) {
            int nch = min(32, cnt - chunk);
            if (chunk) svc = (l32 < nch) ? (int)csr[base + chunk + l32] + gbb : 0;
            int i = 0;
            for (; i + 16 <= nch; i += 16) {
                int e[16]; unsigned u[16];
#pragma unroll
                for (int k = 0; k < 16; k++) e[k] = __shfl(svc, hbase + i + k);
#pragma unroll
                for (int k = 0; k < 16; k++)
                    u[k] = *(const unsigned*)(xbb + (unsigned)(e[k] + l32_4));
#pragma unroll
                for (int k = 0; k < 16; k++) {
                    h2 h = __builtin_bit_cast(h2, u[k]);
                    acx[k & 3] = fdot2(h, one0,  acx[k & 3]);
                    acy[k & 3] = fdot2(h, zero1, acy[k & 3]);
                }
            }
            for (; i + 8 <= nch; i += 8) {
                int e[8]; unsigned u[8];
#pragma unroll
                for (int k = 0; k < 8; k++) e[k] = __shfl(svc, hbase + i + k);
#pragma unroll
                for (int k = 0; k < 8; k++)
                    u[k] = *(const unsigned*)(xbb + (unsigned)(e[k] + l32_4));
#pragma unroll
                for (int k = 0; k < 8; k++) {
                    h2 h = __builtin_bit_cast(h2, u[k]);
                    acx[k & 3] = fdot2(h, one0,  acx[k & 3]);
                    acy[k & 3] = fdot2(h, zero1, acy[k & 3]);
                }
            }
            for (; i + 4 <= nch; i += 4) {
                int e[4]; unsigned u[4];
#pragma unroll
                for (int k = 0; k < 4; k++) e[k] = __shfl(svc, hbase + i + k);
#pragma unroll
                for (int k = 0; k < 4; k++)
                    u[k] = *(const unsigned*)(xbb + (unsigned)(e[k] + l32_4));
#pragma unroll
                for (int k = 0; k < 4; k++) {
                    h2 h = __builtin_bit_cast(h2, u[k]);
                    acx[k] = fdot2(h, one0,  acx[k]);
                    acy[k] = fdot2(h, zero1, acy[k]);
                }
            }
            for (; i < nch; i++) {
                int e = __shfl(svc, hbase + i);
                h2 h = __builtin_bit_cast(h2, *(const unsigned*)(xbb + (unsigned)(e + l32_4)));
                acx[0] = fdot2(h, one0,  acx[0]);
                acy[0] = fdot2(h, zero1, acy[0]);
            }
        }
        // self-loop term
        {
            h2 sh = __builtin_bit_cast(h2, selfu);
            acx[0] = fdot2(sh, one0,  acx[0]);
            acy[0] = fdot2(sh, zero1, acy[0]);
        }
        float rd = rsqrtf((float)(cnt + 1));
        float2 o;
        o.x = ((acx[0] + acx[1]) + (acx[2] + acx[3])) * rd;
        o.y = ((acy[0] + acy[1]) + (acy[2] + acy[3])) * rd;
        // swizzled store: dwords d=2*l32..+1 -> 16B chunk (l32>>1)^(rloc&7)
        int pi = rloc * 32 + ((((l32 >> 1) ^ (rloc & 7)) << 1) | (l32 & 1));
        ((float2*)ls)[pi] = o;
        ni = ni_n; sv = sv_n; gbb = gbb_n;
    }
    __syncthreads();

    // ---- phase 2: conv = relu(agg @ W + b), score = tanh(conv.p/||p||) ----
    const h8* wsrc = wfrag + (GATE ? 1024 : 0);
    int q = lane >> 4, c = lane & 15;
    int rl16 = (wid * 16 + c) * 16;            // float4 row base in LDS
    int cx = c & 7;
    h8 ah[2], al[2];
#pragma unroll
    for (int ks = 0; ks < 2; ks++) {
        float4 v0 = ls4[rl16 + ((ks * 8 + q * 2 + 0) ^ cx)];
        float4 v1 = ls4[rl16 + ((ks * 8 + q * 2 + 1) ^ cx)];
        float vv[8] = {v0.x, v0.y, v0.z, v0.w, v1.x, v1.y, v1.z, v1.w};
        h8 h, l;
#pragma unroll
        for (int j = 0; j < 8; j += 2) {
            h2 hp = pkrtz(vv[j], vv[j + 1]);
            float r0 = vv[j]     - (float)hp.x;
            float r1 = vv[j + 1] - (float)hp.y;
            h2 lp = pkrtz(r0, r1);
            h[j] = hp.x; h[j + 1] = hp.y;
            l[j] = lp.x; l[j + 1] = lp.y;
        }
        ah[ks] = h; al[ks] = l;
    }
    float pp = 0.f;
#pragma unroll
    for (int i = 0; i < DIM_; i++) pp += pvec[i] * pvec[i];
    float rpn = rsqrtf(pp);
    float dot[4] = {0.f, 0.f, 0.f, 0.f};
#pragma unroll
    for (int nt = 0; nt < 4; nt++) {
        f4 acc = {0.f, 0.f, 0.f, 0.f};
#pragma unroll
        for (int ks = 0; ks < 2; ks++) {
            h8 wh = wsrc[(((ks * 4 + nt) * 2 + 0) * 64) + lane];
            h8 wl = wsrc[(((ks * 4 + nt) * 2 + 1) * 64) + lane];
            acc = __builtin_amdgcn_mfma_f32_16x16x32_f16(ah[ks], wh, acc, 0, 0, 0);
            acc = __builtin_amdgcn_mfma_f32_16x16x32_f16(ah[ks], wl, acc, 0, 0, 0);
            acc = __builtin_amdgcn_mfma_f32_16x16x32_f16(al[ks], wh, acc, 0, 0, 0);
        }
        float bcol = bias[nt * 16 + c];
        float pcol = pvec[nt * 16 + c];
        float st[4];
#pragma unroll
        for (int reg = 0; reg < 4; reg++) {
            float v = fmaxf(acc[reg] + bcol, 0.f);
            st[reg] = v;
            dot[reg] += v * pcol;
        }
#pragma unroll
        for (int reg = 0; reg < 4; reg++)
            y[(size_t)(wg * 64 + wid * 16 + q * 4 + reg) * DIM_ + nt * 16 + c] = st[reg];
    }
#pragma unroll
    for (int m = 1; m < 16; m <<= 1) {
#pragma unroll
        for (int reg = 0; reg < 4; reg++) dot[reg] += __shfl_xor(dot[reg], m);
    }
    if (c == 0) {
#pragma unroll
        for (int reg = 0; reg < 4; reg++)
            score[wg * 64 + wid * 16 + q * 4 + reg] = tanhf(dot[reg] * rpn);
    }
}

// ---------------- exact K-th-largest key per graph (6-pass radix) --------------
template<int STAGE>
__launch_bounds__(256)
__global__ void k_thresh(const float* score, unsigned long long* thresh) {
    const int Nin = (STAGE == 1) ? N_ : K1_;
    const int K   = (STAGE == 1) ? K1_ : K2_;
    __shared__ unsigned long long keys[N_];
    __shared__ int bins[256], wsum[4];
    __shared__ unsigned long long s_prefix;
    __shared__ int s_need;
    int g = blockIdx.x, tid = threadIdx.x;
    int l64 = tid & 63, wid = tid >> 6;
    const float* sg = score + (size_t)g * Nin;
    for (int i = tid; i < Nin; i += 256) keys[i] = mk_key(sg[i], i);
    if (tid == 0) { s_need = K; s_prefix = 0ull; }
    __syncthreads();
    for (int shift = 40; shift >= 0; shift -= 8) {
        bins[tid] = 0;
        __syncthreads();
        unsigned long long pref = s_prefix;
        int need = s_need;
        int hi = shift + 8;
        for (int i = tid; i < Nin; i += 256) {
            unsigned long long k = keys[i];
            if ((k >> hi) == pref) atomicAdd(&bins[(int)((k >> shift) & 255)], 1);
        }
        __syncthreads();
        int mine = bins[tid];
        int v = mine;
#pragma unroll
        for (int o = 1; o < 64; o <<= 1) {     // wave suffix scan
            int t = __shfl_down(v, o);
            if (l64 + o < 64) v += t;
        }
        if (l64 == 0) wsum[wid] = v;
        __syncthreads();
        for (int w = wid + 1; w < 4; w++) v += wsum[w];
        int nxt = v - mine;
        if (v >= need && nxt < need) {         // exactly one tid matches
            s_prefix = (pref << 8) | (unsigned long long)tid;
            s_need = need - nxt;
        }
        __syncthreads();
    }
    if (tid == 0) thresh[g] = s_prefix;
}

// ---------------- pool (+rank/newid/xg in stage1), PB_ blocks/graph, threshold handoff ------
template<int STAGE>
__launch_bounds__(256)
__global__ void k_pool(const float* score, const float* conv, const unsigned long long* thresh,
                       int* new_id, unsigned int* xg, float* part) {
    const int Nin = (STAGE == 1) ? N_ : K1_;
    const int RNG = (STAGE == 1) ? (N_ / PB_) : ((K1_ + PB_ - 1) / PB_);  // 256 / 205
    __shared__ int rnk[256];
    __shared__ unsigned char keepf[256];
    __shared__ int wsum[4], s_base[4];
    __shared__ float rmx[4][64], rsm[4][64];
    int b = blockIdx.x;
    int g = b & 63, pb = b >> 6;
    int tid = threadIdx.x;
    int l64 = tid & 63, wid = tid >> 6;
    const float* sg = score + (size_t)g * Nin;
    unsigned long long T = thresh[g];
    int R0 = pb * RNG;
    int R1 = min(R0 + RNG, Nin);
    if (STAGE == 1) {
        int cb = 0;
        for (int i = tid; i < R0; i += 256) cb += (mk_key(sg[i], i) >= T) ? 1 : 0;
#pragma unroll
        for (int o = 32; o; o >>= 1) cb += __shfl_down(cb, o);
        if (l64 == 0) s_base[wid] = cb;
        int i = R0 + tid;
        int keep = (i < R1 && mk_key(sg[i], i) >= T) ? 1 : 0;
        keepf[tid] = (unsigned char)keep;
        int v = keep;
#pragma unroll
        for (int o = 1; o < 64; o <<= 1) {
            int t = __shfl_up(v, o);
            if (l64 >= o) v += t;
        }
        if (l64 == 63) wsum[wid] = v;
        __syncthreads();
        int base = s_base[0] + s_base[1] + s_base[2] + s_base[3];
        int wbase = 0;
        for (int w = 0; w < wid; w++) wbase += wsum[w];
        int r = base + wbase + v - keep;
        rnk[tid] = r;
        if (i < Nin) new_id[g * N_ + i] = keep ? (g * K1_ + r) : -1;
    } else {
        int i = R0 + tid;
        keepf[tid] = (unsigned char)((i < R1 && mk_key(sg[i], i) >= T) ? 1 : 0);
    }
    __syncthreads();
    float mx = -3.402823466e38f, sm = 0.f;
    for (int i = R0 + wid; i < R1; i += 4) {
        if (!keepf[i - R0]) continue;
        float val = sg[i];
        float v = conv[(size_t)(g * Nin + i) * DIM_ + l64] * val;
        mx = fmaxf(mx, v);
        sm += v;
        if (STAGE == 1) {
            float vo = __shfl_xor(v, 1);
            if (!(l64 & 1)) {
                h2 pk2 = {(_Float16)v, (_Float16)vo};
                xg[(size_t)(g * K1_ + rnk[i - R0]) * 32 + (l64 >> 1)] =
                    __builtin_bit_cast(unsigned int, pk2);
            }
        }
    }
    rmx[wid][l64] = mx; rsm[wid][l64] = sm;
    __syncthreads();
    if (wid == 0) {
        mx = fmaxf(fmaxf(rmx[0][l64], rmx[1][l64]), fmaxf(rmx[2][l64], rmx[3][l64]));
        sm = rsm[0][l64] + rsm[1][l64] + rsm[2][l64] + rsm[3][l64];
        part[((size_t)(g * PB_ + pb) * 2 + 0) * 64 + l64] = mx;
        part[((size_t)(g * PB_ + pb) * 2 + 1) * 64 + l64] = sm;
    }
}

// ---------------- MLP head (combines both stages' partials) ----------------
__launch_bounds__(64)
__global__ void k_head(const float* part1, const float* part2,
                       const float* l1w, const float* l1b,
                       const float* l2w, const float* l2b, float* out) {
    __shared__ float h[128];
    __shared__ float h1[64];
    int g = blockIdx.x, t = threadIdx.x;
    float mx1 = -3.402823466e38f, sm1 = 0.f, mx2 = -3.402823466e38f, sm2 = 0.f;
#pragma unroll
    for (int c = 0; c < PB_; c++) {
        mx1 = fmaxf(mx1, part1[((size_t)(g * PB_ + c) * 2 + 0) * 64 + t]);
        sm1 += part1[((size_t)(g * PB_ + c) * 2 + 1) * 64 + t];
        mx2 = fmaxf(mx2, part2[((size_t)(g * PB_ + c) * 2 + 0) * 64 + t]);
        sm2 += part2[((size_t)(g * PB_ + c) * 2 + 1) * 64 + t];
    }
    h[t]      = mx1 + mx2;
    h[t + 64] = sm1 / (float)K1_ + sm2 / (float)K2_;
    __syncthreads();
    float acc = l1b[t];
#pragma unroll 8
    for (int i = 0; i < 128; i++) acc += h[i] * l1w[i * 64 + t];
    h1[t] = fmaxf(acc, 0.0f);
    __syncthreads();
    if (t < NCLS) {
        float o = l2b[t];
#pragma unroll
        for (int i = 0; i < 64; i++) o += h1[i] * l2w[i * NCLS + t];
        out[g * NCLS + t] = o;
    }
}

extern "C" void kernel_launch(void* const* d_in, const int* in_sizes, int n_in,
                              void* d_out, int out_size, void* d_ws, size_t ws_size,
                              hipStream_t stream) {
    const float* x   = (const float*)d_in[0];
    const int*   ei  = (const int*)d_in[1];
    const int*   src = ei;
    const int*   dst = ei + ETOT;
    const float* W1  = (const float*)d_in[3];
    const float* b1  = (const float*)d_in[4];
    const float* p1  = (const float*)d_in[5];
    const float* W2  = (const float*)d_in[6];
    const float* b2  = (const float*)d_in[7];
    const float* p2  = (const float*)d_in[8];
    const float* l1w = (const float*)d_in[9];
    const float* l1b = (const float*)d_in[10];
    const float* l2w = (const float*)d_in[11];
    const float* l2b = (const float*)d_in[12];
    (void)in_sizes; (void)n_in; (void)out_size; (void)ws_size;

    // workspace layout (~92 MB); xg aliases bufB (dead until aggconv2 writes it)
    char* ws = (char*)d_ws;
    size_t off = 0;
    auto alloc = [&](size_t bytes) -> void* {
        void* p = ws + off;
        off = (off + bytes + 255) & ~(size_t)255;
        return p;
    };
    float*              bufA   = (float*)             alloc((size_t)NTOT  * DIM_ * 4);
    float*              bufB   = (float*)             alloc((size_t)N2TOT * DIM_ * 4);
    unsigned int*       blist  = (unsigned int*)      alloc((size_t)B_ * CHUNKS_ * BCAP * 4);
    unsigned int*       xb     = (unsigned int*)      alloc((size_t)NTOT * 32 * 4);
    int*                bcnt   = (int*)               alloc((size_t)B_ * SLICES_ * CHUNKS_ * 4);
    int*                ninfo  = (int*)               alloc((size_t)NTOT * 4);
    float*              score  = (float*)             alloc((size_t)NTOT * 4);
    int*                newid  = (int*)               alloc((size_t)NTOT * 4);
    unsigned long long* thr    = (unsigned long long*)alloc((size_t)B_ * 8);
    float*              part1  = (float*)             alloc((size_t)B_ * PB_ * 128 * 4);
    float*              part2  = (float*)             alloc((size_t)B_ * PB_ * 128 * 4);
    h8*                 wfrag  = (h8*)                alloc((size_t)2048 * 16);
    unsigned int*       xg     = (unsigned int*)bufB;   // alias

    // ---- one-time W fragment prep ----
    k_wprep<<<1, 128, 0, stream>>>(W1, W2, wfrag);

    // ---- stage 1 ----
    k_bucket<1><<<B_ * SLICES_, 256, 0, stream>>>(src, dst, nullptr, bcnt, blist);
    k_sort<1><<<B_ * CHUNKS_, 256, 0, stream>>>(bcnt, blist, x, nullptr, xb, ninfo);
    k_aggconv<false><<<NTOT / 64, 256, 0, stream>>>(xb, ninfo, blist, wfrag, b1, p1, bufA, score);
    k_thresh<1><<<B_, 256, 0, stream>>>(score, thr);
    k_pool<1><<<B_ * PB_, 256, 0, stream>>>(score, bufA, thr, newid, xg, part1);

    // ---- stage 2 ----
    k_bucket<2><<<B_ * SLICES_, 256, 0, stream>>>(src, dst, newid, bcnt, blist);
    k_sort<2><<<B_ * CHUNKS_, 256, 0, stream>>>(bcnt, blist, nullptr, xg, xb, ninfo);
    k_aggconv<true><<<N2TOT / 64, 256, 0, stream>>>(xb, ninfo, blist, wfrag, b2, p2, bufB, score);
    k_thresh<2><<<B_, 256, 0, stream>>>(score, thr);
    k_pool<2><<<B_ * PB_, 256, 0, stream>>>(score, bufB, thr, nullptr, nullptr, part2);

    // ---- head (combines both stages' partials) ----
    k_head<<<B_, 64, 0, stream>>>(part1, part2, l1w, l1b, l2w, l2b, (float*)d_out);
}